// Round 2
// baseline (2938.096 us; speedup 1.0000x reference)
//
#include <hip/hip_runtime.h>
#include <math.h>

constexpr int NN = 100000;   // nodes
constexpr int EE = 3200000;  // edges
constexpr int BB = 32;       // graphs
constexpr int LSEQ = 1000;   // text length
constexpr int DD = 128;      // emb dim
constexpr int NH = 3;        // heads gat1
constexpr int HD = 384;      // 3*128
constexpr int NB1 = (NN + 255) / 256;  // 391 scan blocks

static __device__ __forceinline__ float lrelu(float x) { return x > 0.f ? x : 0.2f * x; }
// manual bf16 <-> f32 (RNE), stored as ushort
static __device__ __forceinline__ float bf2f(unsigned short u) {
  return __uint_as_float(((unsigned)u) << 16);
}
static __device__ __forceinline__ unsigned short f2bf(float f) {
  unsigned x = __float_as_uint(f);
  return (unsigned short)((x + 0x7fffu + ((x >> 16) & 1u)) >> 16);
}

// ---------------- fills ----------------
__global__ void fill_u32(unsigned* p, unsigned v, int n) {
  int i = blockIdx.x * 256 + threadIdx.x;
  if (i < n) p[i] = v;
}

// ---------------- CSR build ----------------
__global__ void hist_k(const int* __restrict__ dst, int* __restrict__ deg) {
  int e = blockIdx.x * 256 + threadIdx.x;
  if (e < EE) atomicAdd(&deg[dst[e]], 1);
}

__global__ void scan1_k(const int* __restrict__ deg, int* __restrict__ excl,
                        int* __restrict__ bsum) {
  __shared__ int tmp[256];
  int tid = threadIdx.x;
  int i = blockIdx.x * 256 + tid;
  int v = (i < NN) ? deg[i] : 0;
  tmp[tid] = v;
  __syncthreads();
  for (int off = 1; off < 256; off <<= 1) {
    int t = (tid >= off) ? tmp[tid - off] : 0;
    __syncthreads();
    tmp[tid] += t;
    __syncthreads();
  }
  if (i < NN) excl[i] = tmp[tid] - v;
  if (tid == 255) bsum[blockIdx.x] = tmp[255];
}

__global__ void scan2_k(int* __restrict__ bsum) {
  if (threadIdx.x == 0 && blockIdx.x == 0) {
    int acc = 0;
    for (int b = 0; b < NB1; ++b) { int t = bsum[b]; bsum[b] = acc; acc += t; }
  }
}

__global__ void scan3_k(const int* __restrict__ excl, const int* __restrict__ bsum,
                        int* __restrict__ offs, int* __restrict__ cursor) {
  int i = blockIdx.x * 256 + threadIdx.x;
  if (i < NN) {
    int o = excl[i] + bsum[blockIdx.x];
    offs[i] = o;
    cursor[i] = o;
  }
}

__global__ void scatter_k(const int* __restrict__ src, const int* __restrict__ dst,
                          int* __restrict__ cursor, int* __restrict__ srcs) {
  int e = blockIdx.x * 256 + threadIdx.x;
  if (e >= EE) return;
  int pos = atomicAdd(&cursor[dst[e]], 1);
  srcs[pos] = src[e];
}

// ---------------- tiled GEMM: C[M,Nc] = A[M,K] @ W[K,Nc] ----------------
// BM=BN=128, BK=8, 256 threads, 8x8 per thread. K%8==0, Nc%128==0.
// ABF: A is bf16(ushort) else f32.  C written as bf16(ushort).
template <bool ABF>
__global__ __launch_bounds__(256) void sgemm_bf(const void* __restrict__ Av,
                                                const float* __restrict__ W,
                                                unsigned short* __restrict__ C,
                                                int M, int K, int Nc) {
  __shared__ float As[8][128];
  __shared__ float Bs[8][128];
  int bm = blockIdx.y * 128;
  int bn = blockIdx.x * 128;
  int tid = threadIdx.x;
  int tx = tid % 16, ty = tid / 16;
  float acc[8][8] = {};
  for (int k0 = 0; k0 < K; k0 += 8) {
    {
      int r = tid / 2;
      int c = (tid % 2) * 4;
      int gr = bm + r;
      float x0 = 0.f, x1 = 0.f, x2 = 0.f, x3 = 0.f;
      if (gr < M) {
        if constexpr (ABF) {
          const unsigned short* A = (const unsigned short*)Av;
          ushort4 v = *(const ushort4*)(A + (size_t)gr * K + k0 + c);
          x0 = bf2f(v.x); x1 = bf2f(v.y); x2 = bf2f(v.z); x3 = bf2f(v.w);
        } else {
          const float* A = (const float*)Av;
          float4 v = *(const float4*)(A + (size_t)gr * K + k0 + c);
          x0 = v.x; x1 = v.y; x2 = v.z; x3 = v.w;
        }
      }
      As[c + 0][r] = x0; As[c + 1][r] = x1; As[c + 2][r] = x2; As[c + 3][r] = x3;
    }
    {
      int r = tid / 32;
      int c = (tid % 32) * 4;
      float4 v = *(const float4*)(W + (size_t)(k0 + r) * Nc + bn + c);
      *(float4*)&Bs[r][c] = v;
    }
    __syncthreads();
#pragma unroll
    for (int kk = 0; kk < 8; ++kk) {
      float a[8], b[8];
#pragma unroll
      for (int i = 0; i < 8; ++i) a[i] = As[kk][ty * 8 + i];
#pragma unroll
      for (int j = 0; j < 8; ++j) b[j] = Bs[kk][tx * 8 + j];
#pragma unroll
      for (int i = 0; i < 8; ++i)
#pragma unroll
        for (int j = 0; j < 8; ++j) acc[i][j] += a[i] * b[j];
    }
    __syncthreads();
  }
#pragma unroll
  for (int i = 0; i < 8; ++i) {
    int gr = bm + ty * 8 + i;
    if (gr >= M) continue;
#pragma unroll
    for (int j = 0; j < 8; ++j) {
      int gc = bn + tx * 8 + j;
      C[(size_t)gr * Nc + gc] = f2bf(acc[i][j]);
    }
  }
}

// ---------------- el/er ----------------
__global__ void elr_k1(const unsigned short* __restrict__ h, const float* __restrict__ al,
                       const float* __restrict__ ar, float* __restrict__ el,
                       float* __restrict__ er) {
  int wid = (blockIdx.x * 256 + threadIdx.x) >> 6;
  int lane = threadIdx.x & 63;
  if (wid >= NN * NH) return;
  int n = wid / NH, hh = wid % NH;
  const unsigned short* row = h + (size_t)n * HD + hh * DD;
  const float* a = al + hh * DD;
  const float* r = ar + hh * DD;
  int c = lane * 2;
  unsigned v = *(const unsigned*)(row + c);
  float x0 = bf2f((unsigned short)(v & 0xffffu));
  float x1 = bf2f((unsigned short)(v >> 16));
  float pel = x0 * a[c] + x1 * a[c + 1];
  float per = x0 * r[c] + x1 * r[c + 1];
#pragma unroll
  for (int off = 32; off; off >>= 1) {
    pel += __shfl_down(pel, off);
    per += __shfl_down(per, off);
  }
  if (lane == 0) { el[wid] = pel; er[wid] = per; }
}

__global__ void elr_k2(const unsigned short* __restrict__ h, const float* __restrict__ al,
                       const float* __restrict__ ar, float* __restrict__ el,
                       float* __restrict__ er) {
  int wid = (blockIdx.x * 256 + threadIdx.x) >> 6;
  int lane = threadIdx.x & 63;
  if (wid >= NN) return;
  const unsigned short* row = h + (size_t)wid * HD;
  float pel = 0.f, per = 0.f;
#pragma unroll
  for (int k = 0; k < 3; ++k) {
    int c = lane * 2 + k * 128;
    unsigned v = *(const unsigned*)(row + c);
    float x0 = bf2f((unsigned short)(v & 0xffffu));
    float x1 = bf2f((unsigned short)(v >> 16));
    pel += x0 * al[c] + x1 * al[c + 1];
    per += x0 * ar[c] + x1 * ar[c + 1];
  }
#pragma unroll
  for (int off = 32; off; off >>= 1) {
    pel += __shfl_down(pel, off);
    per += __shfl_down(per, off);
  }
  if (lane == 0) { el[wid] = pel; er[wid] = per; }
}

// ---------------- fused edge-softmax + aggregation (wave per dst node) ----------------
template <int H>
__global__ void agg_csr(const int* __restrict__ offs, const int* __restrict__ deg,
                        const int* __restrict__ srcs,
                        const float* __restrict__ el, const float* __restrict__ er,
                        const unsigned short* __restrict__ hfeat,
                        const float* __restrict__ bias,
                        unsigned short* __restrict__ outg) {
  int wid = (blockIdx.x * 256 + threadIdx.x) >> 6;
  int lane = threadIdx.x & 63;
  if (wid >= NN) return;
  int d = wid;
  int o0 = offs[d], dg = deg[d];
  float erd[H], mh[H], wsum[H];
#pragma unroll
  for (int h = 0; h < H; ++h) { erd[h] = er[d * H + h]; mh[h] = -1e30f; wsum[h] = 0.f; }
  for (int j = 0; j < dg; ++j) {
    int s = srcs[o0 + j];
#pragma unroll
    for (int h = 0; h < H; ++h) mh[h] = fmaxf(mh[h], lrelu(el[s * H + h] + erd[h]));
  }
  float acc0[3] = {0.f, 0.f, 0.f}, acc1[3] = {0.f, 0.f, 0.f};
  for (int j = 0; j < dg; ++j) {
    int s = srcs[o0 + j];
    float w[H];
#pragma unroll
    for (int h = 0; h < H; ++h) {
      w[h] = __expf(lrelu(el[s * H + h] + erd[h]) - mh[h]);
      wsum[h] += w[h];
    }
    const unsigned short* hrow = hfeat + (size_t)s * HD;
#pragma unroll
    for (int k = 0; k < 3; ++k) {
      unsigned v = *(const unsigned*)(hrow + lane * 2 + k * 128);
      float wk = (H == 1) ? w[0] : w[k];
      acc0[k] += wk * bf2f((unsigned short)(v & 0xffffu));
      acc1[k] += wk * bf2f((unsigned short)(v >> 16));
    }
  }
  unsigned short* orow = outg + (size_t)d * HD;
#pragma unroll
  for (int k = 0; k < 3; ++k) {
    int c = lane * 2 + k * 128;
    float inv = (dg > 0) ? 1.f / ((H == 1) ? wsum[0] : wsum[k]) : 0.f;
    float a = fmaxf(acc0[k] * inv + bias[c], 0.f);
    float b = fmaxf(acc1[k] * inv + bias[c + 1], 0.f);
    unsigned pv = (unsigned)f2bf(a) | ((unsigned)f2bf(b) << 16);
    *(unsigned*)(orow + c) = pv;
  }
}

// ---------------- graph max pool (graph_ids sorted; values >= 0) ----------------
__global__ void graph_pool(const unsigned short* __restrict__ g, const int* __restrict__ gid,
                           unsigned* __restrict__ gp) {
  int c = threadIdx.x;              // 0..383
  int n0 = blockIdx.x * 64;
  int nend = min(n0 + 64, NN);
  int cur = gid[n0];
  float mx = 0.f;
  for (int n = n0; n < nend; ++n) {
    int gg = gid[n];
    if (gg != cur) {
      atomicMax(&gp[cur * HD + c], __float_as_uint(mx));
      cur = gg; mx = 0.f;
    }
    mx = fmaxf(mx, bf2f(g[(size_t)n * HD + c]));
  }
  atomicMax(&gp[cur * HD + c], __float_as_uint(mx));
}

// ---------------- CNN branch ----------------
__global__ void transpose_x(const float* __restrict__ pad, float* __restrict__ xT) {
  size_t idx = (size_t)blockIdx.x * 256 + threadIdx.x;
  if (idx >= (size_t)BB * 128 * LSEQ) return;
  int l = idx % LSEQ;
  int i = (idx / LSEQ) % 128;
  int b = idx / (128 * LSEQ);
  xT[idx] = pad[((size_t)b * LSEQ + l) * DD + i];
}

__global__ void conv1d_k(const float* __restrict__ x, int Lin,
                         const float* __restrict__ w, const float* __restrict__ bias,
                         float* __restrict__ out, int Lout) {
  int l = blockIdx.x * 256 + threadIdx.x;
  int o = blockIdx.y;
  int b = blockIdx.z;
  if (l >= Lout) return;
  float acc = bias[o];
  const float* wrow = w + (size_t)o * 128 * 3;
  const float* xb = x + (size_t)b * 128 * Lin;
  for (int i = 0; i < 128; ++i) {
    const float* xr = xb + (size_t)i * Lin + l;
    acc += xr[0] * wrow[i * 3 + 0] + xr[1] * wrow[i * 3 + 1] + xr[2] * wrow[i * 3 + 2];
  }
  out[((size_t)b * 128 + o) * Lout + l] = acc;
}

__global__ void maxpool_k(const float* __restrict__ in, float* __restrict__ out,
                          int Lin, int Lout, int k, int s, int total) {
  int idx = blockIdx.x * 256 + threadIdx.x;
  if (idx >= total) return;
  int j = idx % Lout;
  size_t row = idx / Lout;
  const float* r = in + row * Lin + (size_t)j * s;
  float m = r[0];
  for (int t = 1; t < k; ++t) m = fmaxf(m, r[t]);
  out[idx] = m;
}

// ---------------- small matmuls (M == 32 rows) ----------------
__global__ void small_mm(const float* __restrict__ A, const float* __restrict__ W,
                         const float* __restrict__ bias, float* __restrict__ C,
                         int M, int K, int Nc, int doRelu) {
  int row = threadIdx.x >> 3;
  int col = blockIdx.x * 8 + (threadIdx.x & 7);
  if (row >= M || col >= Nc) return;
  float acc = bias ? bias[col] : 0.f;
  for (int k = 0; k < K; ++k) acc += A[(size_t)row * K + k] * W[(size_t)k * Nc + col];
  if (doRelu) acc = fmaxf(acc, 0.f);
  C[(size_t)row * Nc + col] = acc;
}

__global__ void fuse_k(const float* __restrict__ g1fc, const float* __restrict__ seq1,
                       const float* __restrict__ w1, float* __restrict__ gc) {
  int i = blockIdx.x * 256 + threadIdx.x;
  if (i >= BB * 128) return;
  float wv = 1.f / (1.f + __expf(-w1[0]));
  gc[i] = (1.f - wv) * g1fc[i] + wv * seq1[i];
}

__global__ void head_k(const float* __restrict__ gc2, const float* __restrict__ ow,
                       const float* __restrict__ ob, float* __restrict__ out) {
  int b = threadIdx.x;
  if (b >= BB) return;
  float o0 = ob[0], o1 = ob[1];
  for (int k = 0; k < 256; ++k) {
    float v = gc2[b * 256 + k];
    o0 += v * ow[k * 2 + 0];
    o1 += v * ow[k * 2 + 1];
  }
  o0 = fmaxf(o0, 0.f); o1 = fmaxf(o1, 0.f);
  float mm = fmaxf(o0, o1);
  float e0 = __expf(o0 - mm), e1 = __expf(o1 - mm);
  float inv = 1.f / (e0 + e1);
  out[b * 2 + 0] = e0 * inv;
  out[b * 2 + 1] = e1 * inv;
}

extern "C" void kernel_launch(void* const* d_in, const int* in_sizes, int n_in,
                              void* d_out, int out_size, void* d_ws, size_t ws_size,
                              hipStream_t stream) {
  const float* node_feat = (const float*)d_in[0];
  const int*   src  = (const int*)d_in[1];
  const int*   dst  = (const int*)d_in[2];
  const int*   gids = (const int*)d_in[3];
  const float* pad  = (const float*)d_in[4];
  const float* W1   = (const float*)d_in[5];
  const float* al1  = (const float*)d_in[6];
  const float* ar1  = (const float*)d_in[7];
  const float* b1   = (const float*)d_in[8];
  const float* W2   = (const float*)d_in[9];
  const float* al2  = (const float*)d_in[10];
  const float* ar2  = (const float*)d_in[11];
  const float* b2   = (const float*)d_in[12];
  const float* fcgw = (const float*)d_in[13];
  const float* fcgb = (const float*)d_in[14];
  const float* c1w  = (const float*)d_in[15];
  const float* c1b  = (const float*)d_in[16];
  const float* c2w  = (const float*)d_in[17];
  const float* c2b  = (const float*)d_in[18];
  const float* c3w  = (const float*)d_in[19];
  const float* c3b  = (const float*)d_in[20];
  const float* tfw  = (const float*)d_in[21];
  const float* tfb  = (const float*)d_in[22];
  const float* w1s  = (const float*)d_in[23];
  const float* fc1w = (const float*)d_in[24];
  const float* fc1b = (const float*)d_in[25];
  const float* fc2w = (const float*)d_in[26];
  const float* fc2b = (const float*)d_in[27];
  const float* outw = (const float*)d_in[28];
  const float* outb = (const float*)d_in[29];
  float* out = (float*)d_out;
  char* base = (char*)d_ws;

  // -------- workspace layout (bytes) --------
  constexpr size_t SZ_BIG = (size_t)NN * HD * 2;      // 76.8 MB (bf16 N x 384)
  unsigned short* hA = (unsigned short*)(base + 0);   // region A
  unsigned short* gB = (unsigned short*)(base + SZ_BIG);  // region B
  size_t o = 2 * SZ_BIG;
  int* deg    = (int*)(base + o); o += (size_t)NN * 4;
  int* offs   = (int*)(base + o); o += (size_t)NN * 4;
  int* cursor = (int*)(base + o); o += (size_t)NN * 4;
  int* excl   = (int*)(base + o); o += (size_t)NN * 4;
  int* bsum   = (int*)(base + o); o += 2048;
  int* srcs   = (int*)(base + o); o += (size_t)EE * 4;
  float* el1  = (float*)(base + o); o += (size_t)NN * NH * 4;
  float* er1  = (float*)(base + o); o += (size_t)NN * NH * 4;
  float* el2  = (float*)(base + o); o += (size_t)NN * 4;
  float* er2  = (float*)(base + o); o += (size_t)NN * 4;
  unsigned* gpool = (unsigned*)(base + o); o += (size_t)BB * HD * 4;
  float* g1fc = (float*)(base + o); o += BB * 128 * 4;
  float* fvec = (float*)(base + o); o += BB * 128 * 4;
  float* seq1 = (float*)(base + o); o += BB * 128 * 4;
  float* gcv  = (float*)(base + o); o += BB * 128 * 4;
  float* gc1  = (float*)(base + o); o += BB * 512 * 4;
  float* gc2  = (float*)(base + o); o += BB * 256 * 4;

  // CNN scratch lives inside region A (dead before first GEMM writes hA)
  float* xT = (float*)base;                         // [B,128,1000]
  float* c1 = xT + (size_t)BB * 128 * LSEQ;         // [B,128,998]
  float* p1 = c1 + (size_t)BB * 128 * 998;          // [B,128,332]
  float* c2 = p1 + (size_t)BB * 128 * 332;          // [B,128,330]
  float* p2 = c2 + (size_t)BB * 128 * 330;          // [B,128,110]
  float* c3 = p2 + (size_t)BB * 128 * 110;          // [B,128,108]

  // -------- CNN branch --------
  {
    size_t tot = (size_t)BB * 128 * LSEQ;
    transpose_x<<<(int)((tot + 255) / 256), 256, 0, stream>>>(pad, xT);
  }
  conv1d_k<<<dim3(4, 128, BB), 256, 0, stream>>>(xT, LSEQ, c1w, c1b, c1, 998);
  {
    int tot = BB * 128 * 332;
    maxpool_k<<<(tot + 255) / 256, 256, 0, stream>>>(c1, p1, 998, 332, 3, 3, tot);
  }
  conv1d_k<<<dim3(2, 128, BB), 256, 0, stream>>>(p1, 332, c2w, c2b, c2, 330);
  {
    int tot = BB * 128 * 110;
    maxpool_k<<<(tot + 255) / 256, 256, 0, stream>>>(c2, p2, 330, 110, 3, 3, tot);
  }
  conv1d_k<<<dim3(1, 128, BB), 256, 0, stream>>>(p2, 110, c3w, c3b, c3, 108);
  {
    int tot = BB * 128;
    maxpool_k<<<(tot + 255) / 256, 256, 0, stream>>>(c3, fvec, 108, 1, 108, 1, tot);
  }
  small_mm<<<16, 256, 0, stream>>>(fvec, tfw, tfb, seq1, 32, 128, 128, 1);

  // -------- CSR build (once; shared by both GAT layers) --------
  fill_u32<<<NB1, 256, 0, stream>>>((unsigned*)deg, 0u, NN);
  hist_k<<<EE / 256, 256, 0, stream>>>(dst, deg);
  scan1_k<<<NB1, 256, 0, stream>>>(deg, excl, bsum);
  scan2_k<<<1, 64, 0, stream>>>(bsum);
  scan3_k<<<NB1, 256, 0, stream>>>(excl, bsum, offs, cursor);
  scatter_k<<<EE / 256, 256, 0, stream>>>(src, dst, cursor, srcs);

  // -------- GAT layer 1 --------
  sgemm_bf<false><<<dim3(HD / 128, (NN + 127) / 128), 256, 0, stream>>>(node_feat, W1, hA, NN, DD, HD);
  elr_k1<<<(NN * NH * 64 + 255) / 256, 256, 0, stream>>>(hA, al1, ar1, el1, er1);
  agg_csr<3><<<(NN * 64 + 255) / 256, 256, 0, stream>>>(offs, deg, srcs, el1, er1, hA, b1, gB);

  // -------- GAT layer 2 --------
  sgemm_bf<true><<<dim3(HD / 128, (NN + 127) / 128), 256, 0, stream>>>(gB, W2, hA, NN, HD, HD);
  elr_k2<<<(NN * 64 + 255) / 256, 256, 0, stream>>>(hA, al2, ar2, el2, er2);
  agg_csr<1><<<(NN * 64 + 255) / 256, 256, 0, stream>>>(offs, deg, srcs, el2, er2, hA, b2, gB);

  // -------- graph pooling + head --------
  fill_u32<<<(BB * HD + 255) / 256, 256, 0, stream>>>(gpool, 0u, BB * HD);
  graph_pool<<<(NN + 63) / 64, 384, 0, stream>>>(gB, gids, gpool);
  small_mm<<<16, 256, 0, stream>>>((const float*)gpool, fcgw, fcgb, g1fc, 32, HD, 128, 1);
  fuse_k<<<16, 256, 0, stream>>>(g1fc, seq1, w1s, gcv);
  small_mm<<<64, 256, 0, stream>>>(gcv, fc1w, fc1b, gc1, 32, 128, 512, 1);
  small_mm<<<32, 256, 0, stream>>>(gc1, fc2w, fc2b, gc2, 32, 512, 256, 1);
  head_k<<<1, 64, 0, stream>>>(gc2, outw, outb, out);
}

// Round 3
// 2104.904 us; speedup vs baseline: 1.3958x; 1.3958x over previous
//
#include <hip/hip_runtime.h>
#include <math.h>

constexpr int NN = 100000;   // nodes
constexpr int EE = 3200000;  // edges
constexpr int BB = 32;       // graphs
constexpr int LSEQ = 1000;   // text length
constexpr int DD = 128;      // emb dim
constexpr int NH = 3;        // heads gat1
constexpr int HD = 384;      // 3*128
constexpr int NB1 = (NN + 255) / 256;  // scan blocks

typedef __attribute__((ext_vector_type(8))) short bf16v8;
typedef __attribute__((ext_vector_type(4))) float f32x4;

static __device__ __forceinline__ float lrelu(float x) { return x > 0.f ? x : 0.2f * x; }
static __device__ __forceinline__ float bf2f(unsigned short u) {
  return __uint_as_float(((unsigned)u) << 16);
}
static __device__ __forceinline__ unsigned short f2bf(float f) {
  unsigned x = __float_as_uint(f);
  return (unsigned short)((x + 0x7fffu + ((x >> 16) & 1u)) >> 16);
}

// ---------------- fills / converts ----------------
__global__ void fill_u32(unsigned* p, unsigned v, int n) {
  int i = blockIdx.x * 256 + threadIdx.x;
  if (i < n) p[i] = v;
}

__global__ void f2bf_vec(const float* __restrict__ in, unsigned short* __restrict__ out, int n4) {
  int i = blockIdx.x * 256 + threadIdx.x;
  if (i >= n4) return;
  float4 v = ((const float4*)in)[i];
  ushort4 o;
  o.x = f2bf(v.x); o.y = f2bf(v.y); o.z = f2bf(v.z); o.w = f2bf(v.w);
  ((ushort4*)out)[i] = o;
}

// out[n*K+k] = bf16(in[k*N+n])   (transpose + convert, small weights)
__global__ void transp_w(const float* __restrict__ in, unsigned short* __restrict__ out,
                         int K, int N) {
  int id = blockIdx.x * 256 + threadIdx.x;
  if (id >= K * N) return;
  int n = id / K, k = id % K;
  out[id] = f2bf(in[(size_t)k * N + n]);
}

// ---------------- CSR build ----------------
__global__ void hist_k(const int* __restrict__ dst, int* __restrict__ deg) {
  int e = blockIdx.x * 256 + threadIdx.x;
  if (e < EE) atomicAdd(&deg[dst[e]], 1);
}

__global__ void scan1_k(const int* __restrict__ deg, int* __restrict__ excl,
                        int* __restrict__ bsum) {
  __shared__ int tmp[256];
  int tid = threadIdx.x;
  int i = blockIdx.x * 256 + tid;
  int v = (i < NN) ? deg[i] : 0;
  tmp[tid] = v;
  __syncthreads();
  for (int off = 1; off < 256; off <<= 1) {
    int t = (tid >= off) ? tmp[tid - off] : 0;
    __syncthreads();
    tmp[tid] += t;
    __syncthreads();
  }
  if (i < NN) excl[i] = tmp[tid] - v;
  if (tid == 255) bsum[blockIdx.x] = tmp[255];
}

__global__ void scan2_k(int* __restrict__ bsum) {
  if (threadIdx.x == 0 && blockIdx.x == 0) {
    int acc = 0;
    for (int b = 0; b < NB1; ++b) { int t = bsum[b]; bsum[b] = acc; acc += t; }
  }
}

__global__ void scan3_k(const int* __restrict__ excl, const int* __restrict__ bsum,
                        int* __restrict__ offs, int* __restrict__ cursor) {
  int i = blockIdx.x * 256 + threadIdx.x;
  if (i < NN) {
    int o = excl[i] + bsum[blockIdx.x];
    offs[i] = o;
    cursor[i] = o;
  }
}

__global__ void scatter_k(const int* __restrict__ src, const int* __restrict__ dst,
                          int* __restrict__ cursor, int* __restrict__ srcs) {
  int e = blockIdx.x * 256 + threadIdx.x;
  if (e >= EE) return;
  int pos = atomicAdd(&cursor[dst[e]], 1);
  srcs[pos] = src[e];
}

// ---------------- MFMA bf16 GEMM: C[M,Nc] = A[M,K] @ Bt[Nc,K]^T ----------------
// 128x128 tile, BK=64, 4 waves (2x2), global_load_lds w/ pre-swizzled source.
__global__ __launch_bounds__(256) void gemm_mfma(const unsigned short* __restrict__ A,
                                                 const unsigned short* __restrict__ Bt,
                                                 unsigned short* __restrict__ C,
                                                 int M, int K, int Nc) {
  __shared__ unsigned short As[128 * 64];
  __shared__ unsigned short Bs[128 * 64];
  int lane = threadIdx.x & 63;
  int wave = threadIdx.x >> 6;
  int wm = wave >> 1, wn = wave & 1;
  int tile_m = blockIdx.y * 128;
  int tile_n = blockIdx.x * 128;
  int maxRa = M - 1 - tile_m;           // for row clamping (stores are masked)
  f32x4 acc[4][4];
#pragma unroll
  for (int i = 0; i < 4; ++i)
#pragma unroll
    for (int j = 0; j < 4; ++j) acc[i][j] = (f32x4){0.f, 0.f, 0.f, 0.f};

  const unsigned short* Ab = A + (size_t)tile_m * K;
  const unsigned short* Bb = Bt + (size_t)tile_n * K;
  int rloc = (lane >> 3);               // 0..7 within instr
  int cs = (lane & 7) ^ rloc;           // swizzled source chunk (inverse of read XOR)

  for (int k0 = 0; k0 < K; k0 += 64) {
#pragma unroll
    for (int q = 0; q < 4; ++q) {
      int t = wave * 4 + q;
      int r = t * 8 + rloc;
      int ra = r > maxRa ? maxRa : r;
      __builtin_amdgcn_global_load_lds(
          (const __attribute__((address_space(1))) void*)(Ab + (size_t)ra * K + k0 + cs * 8),
          (__attribute__((address_space(3))) void*)(As + t * 512), 16, 0, 0);
      __builtin_amdgcn_global_load_lds(
          (const __attribute__((address_space(1))) void*)(Bb + (size_t)r * K + k0 + cs * 8),
          (__attribute__((address_space(3))) void*)(Bs + t * 512), 16, 0, 0);
    }
    __syncthreads();
#pragma unroll
    for (int ks = 0; ks < 2; ++ks) {
      int q = ks * 4 + (lane >> 4);
      bf16v8 af[4], bfr[4];
#pragma unroll
      for (int i = 0; i < 4; ++i) {
        int r = wm * 64 + i * 16 + (lane & 15);
        af[i] = *(const bf16v8*)&As[r * 64 + ((q ^ (r & 7)) * 8)];
      }
#pragma unroll
      for (int j = 0; j < 4; ++j) {
        int r = wn * 64 + j * 16 + (lane & 15);
        bfr[j] = *(const bf16v8*)&Bs[r * 64 + ((q ^ (r & 7)) * 8)];
      }
#pragma unroll
      for (int i = 0; i < 4; ++i)
#pragma unroll
        for (int j = 0; j < 4; ++j)
          acc[i][j] = __builtin_amdgcn_mfma_f32_16x16x32_bf16(af[i], bfr[j], acc[i][j], 0, 0, 0);
    }
    __syncthreads();
  }
#pragma unroll
  for (int i = 0; i < 4; ++i) {
    int row0 = tile_m + wm * 64 + i * 16 + (lane >> 4) * 4;
#pragma unroll
    for (int j = 0; j < 4; ++j) {
      int col = tile_n + wn * 64 + j * 16 + (lane & 15);
#pragma unroll
      for (int p = 0; p < 4; ++p) {
        int row = row0 + p;
        if (row < M) C[(size_t)row * Nc + col] = f2bf(acc[i][j][p]);
      }
    }
  }
}

// ---------------- el/er ----------------
__global__ void elr_k1(const unsigned short* __restrict__ h, const float* __restrict__ al,
                       const float* __restrict__ ar, float* __restrict__ el,
                       float* __restrict__ er) {
  int wid = (blockIdx.x * 256 + threadIdx.x) >> 6;
  int lane = threadIdx.x & 63;
  if (wid >= NN * NH) return;
  int n = wid / NH, hh = wid % NH;
  const unsigned short* row = h + (size_t)n * HD + hh * DD;
  const float* a = al + hh * DD;
  const float* r = ar + hh * DD;
  int c = lane * 2;
  unsigned v = *(const unsigned*)(row + c);
  float x0 = bf2f((unsigned short)(v & 0xffffu));
  float x1 = bf2f((unsigned short)(v >> 16));
  float pel = x0 * a[c] + x1 * a[c + 1];
  float per = x0 * r[c] + x1 * r[c + 1];
#pragma unroll
  for (int off = 32; off; off >>= 1) {
    pel += __shfl_down(pel, off);
    per += __shfl_down(per, off);
  }
  if (lane == 0) { el[wid] = pel; er[wid] = per; }
}

__global__ void elr_k2(const unsigned short* __restrict__ h, const float* __restrict__ al,
                       const float* __restrict__ ar, float* __restrict__ el,
                       float* __restrict__ er) {
  int wid = (blockIdx.x * 256 + threadIdx.x) >> 6;
  int lane = threadIdx.x & 63;
  if (wid >= NN) return;
  const unsigned short* row = h + (size_t)wid * HD;
  float pel = 0.f, per = 0.f;
#pragma unroll
  for (int k = 0; k < 3; ++k) {
    int c = lane * 2 + k * 128;
    unsigned v = *(const unsigned*)(row + c);
    float x0 = bf2f((unsigned short)(v & 0xffffu));
    float x1 = bf2f((unsigned short)(v >> 16));
    pel += x0 * al[c] + x1 * al[c + 1];
    per += x0 * ar[c] + x1 * ar[c + 1];
  }
#pragma unroll
  for (int off = 32; off; off >>= 1) {
    pel += __shfl_down(pel, off);
    per += __shfl_down(per, off);
  }
  if (lane == 0) { el[wid] = pel; er[wid] = per; }
}

// ---------------- fused edge softmax + aggregation, v2 ----------------
// wave per dst node; edge-parallel scores (1 edge/lane), weights staged in LDS,
// single aggregation pass with broadcast weights.
template <int H>
static __device__ __forceinline__ void agg_body(const float4 t,
                                                const unsigned short* __restrict__ hfeat,
                                                int lane, float acc0[3], float acc1[3]) {
  int s2 = __float_as_int(t.w);
  const unsigned short* hrow = hfeat + (size_t)s2 * HD;
  unsigned v0 = *(const unsigned*)(hrow + lane * 2);
  unsigned v1 = *(const unsigned*)(hrow + lane * 2 + 128);
  unsigned v2 = *(const unsigned*)(hrow + lane * 2 + 256);
  float w0 = t.x;
  float w1 = (H > 1) ? t.y : t.x;
  float w2 = (H > 1) ? t.z : t.x;
  acc0[0] += w0 * bf2f((unsigned short)(v0 & 0xffffu));
  acc1[0] += w0 * bf2f((unsigned short)(v0 >> 16));
  acc0[1] += w1 * bf2f((unsigned short)(v1 & 0xffffu));
  acc1[1] += w1 * bf2f((unsigned short)(v1 >> 16));
  acc0[2] += w2 * bf2f((unsigned short)(v2 & 0xffffu));
  acc1[2] += w2 * bf2f((unsigned short)(v2 >> 16));
}

template <int H>
__global__ __launch_bounds__(256) void agg_csr2(const int* __restrict__ offs,
                                                const int* __restrict__ deg,
                                                const int* __restrict__ srcs,
                                                const float* __restrict__ el,
                                                const float* __restrict__ er,
                                                const unsigned short* __restrict__ hfeat,
                                                const float* __restrict__ bias,
                                                unsigned short* __restrict__ outg) {
  __shared__ float wb[4][64][4];
  int wave = threadIdx.x >> 6, lane = threadIdx.x & 63;
  int d = blockIdx.x * 4 + wave;          // grid = NN/4 exactly
  int o0 = offs[d], dg = deg[d];
  float erd[H];
#pragma unroll
  for (int h = 0; h < H; ++h) erd[h] = er[d * H + h];
  float acc0[3] = {0.f, 0.f, 0.f}, acc1[3] = {0.f, 0.f, 0.f};
  float wsum[H];
#pragma unroll
  for (int h = 0; h < H; ++h) wsum[h] = 0.f;

  if (dg <= 64) {
    // fast path: each lane owns at most one edge; scores stay in registers
    bool has = lane < dg;
    int s = has ? srcs[o0 + lane] : 0;
    float sc[H], mh[H];
#pragma unroll
    for (int h = 0; h < H; ++h)
      sc[h] = has ? lrelu(el[s * H + h] + erd[h]) : -1e30f;
#pragma unroll
    for (int h = 0; h < H; ++h) {
      mh[h] = sc[h];
#pragma unroll
      for (int off = 1; off < 64; off <<= 1) mh[h] = fmaxf(mh[h], __shfl_xor(mh[h], off));
    }
    float w[H];
#pragma unroll
    for (int h = 0; h < H; ++h) {
      w[h] = has ? __expf(sc[h] - mh[h]) : 0.f;
      wsum[h] = w[h];
    }
    wb[wave][lane][0] = w[0];
    wb[wave][lane][1] = (H > 1) ? w[1] : 0.f;
    wb[wave][lane][2] = (H > 1) ? w[H - 1] : 0.f;
    wb[wave][lane][3] = __int_as_float(s);
#pragma unroll 4
    for (int j = 0; j < dg; ++j) {
      float4 t = *(const float4*)&wb[wave][j][0];
      agg_body<H>(t, hfeat, lane, acc0, acc1);
    }
  } else {
    // general path: chunked
    float mh[H];
#pragma unroll
    for (int h = 0; h < H; ++h) mh[h] = -1e30f;
    for (int e = lane; e < dg; e += 64) {
      int s = srcs[o0 + e];
#pragma unroll
      for (int h = 0; h < H; ++h) mh[h] = fmaxf(mh[h], lrelu(el[s * H + h] + erd[h]));
    }
#pragma unroll
    for (int h = 0; h < H; ++h) {
#pragma unroll
      for (int off = 1; off < 64; off <<= 1) mh[h] = fmaxf(mh[h], __shfl_xor(mh[h], off));
    }
    int nch = (dg + 63) >> 6;
    for (int ch = 0; ch < nch; ++ch) {
      int e = ch * 64 + lane;
      bool has = e < dg;
      int s = has ? srcs[o0 + e] : 0;
      float w[H];
#pragma unroll
      for (int h = 0; h < H; ++h) {
        w[h] = has ? __expf(lrelu(el[s * H + h] + erd[h]) - mh[h]) : 0.f;
        wsum[h] += w[h];
      }
      wb[wave][lane][0] = w[0];
      wb[wave][lane][1] = (H > 1) ? w[1] : 0.f;
      wb[wave][lane][2] = (H > 1) ? w[H - 1] : 0.f;
      wb[wave][lane][3] = __int_as_float(s);
      int cnt = min(64, dg - ch * 64);
#pragma unroll 4
      for (int j = 0; j < cnt; ++j) {
        float4 t = *(const float4*)&wb[wave][j][0];
        agg_body<H>(t, hfeat, lane, acc0, acc1);
      }
    }
  }
  // reduce wsum across lanes
#pragma unroll
  for (int h = 0; h < H; ++h) {
#pragma unroll
    for (int off = 1; off < 64; off <<= 1) wsum[h] += __shfl_xor(wsum[h], off);
  }
  unsigned short* orow = outg + (size_t)d * HD;
#pragma unroll
  for (int k = 0; k < 3; ++k) {
    float sw = (H == 1) ? wsum[0] : wsum[(H > 1) ? k : 0];
    float inv = (dg > 0) ? 1.f / sw : 0.f;
    int c = lane * 2 + k * 128;
    float a = fmaxf(acc0[k] * inv + bias[c], 0.f);
    float b = fmaxf(acc1[k] * inv + bias[c + 1], 0.f);
    unsigned pv = (unsigned)f2bf(a) | ((unsigned)f2bf(b) << 16);
    *(unsigned*)(orow + c) = pv;
  }
}

// ---------------- graph max pool (graph_ids sorted; values >= 0) ----------------
__global__ void graph_pool(const unsigned short* __restrict__ g, const int* __restrict__ gid,
                           unsigned* __restrict__ gp) {
  int c = threadIdx.x;              // 0..383
  int n0 = blockIdx.x * 64;
  int nend = min(n0 + 64, NN);
  int cur = gid[n0];
  float mx = 0.f;
  for (int n = n0; n < nend; ++n) {
    int gg = gid[n];
    if (gg != cur) {
      atomicMax(&gp[cur * HD + c], __float_as_uint(mx));
      cur = gg; mx = 0.f;
    }
    mx = fmaxf(mx, bf2f(g[(size_t)n * HD + c]));
  }
  atomicMax(&gp[cur * HD + c], __float_as_uint(mx));
}

// ---------------- CNN branch ----------------
__global__ void transpose_x(const float* __restrict__ pad, float* __restrict__ xT) {
  size_t idx = (size_t)blockIdx.x * 256 + threadIdx.x;
  if (idx >= (size_t)BB * 128 * LSEQ) return;
  int l = idx % LSEQ;
  int i = (idx / LSEQ) % 128;
  int b = idx / (128 * LSEQ);
  xT[idx] = pad[((size_t)b * LSEQ + l) * DD + i];
}

__global__ void conv1d_k(const float* __restrict__ x, int Lin,
                         const float* __restrict__ w, const float* __restrict__ bias,
                         float* __restrict__ out, int Lout) {
  int l = blockIdx.x * 256 + threadIdx.x;
  int o = blockIdx.y;
  int b = blockIdx.z;
  if (l >= Lout) return;
  float acc = bias[o];
  const float* wrow = w + (size_t)o * 128 * 3;
  const float* xb = x + (size_t)b * 128 * Lin;
  for (int i = 0; i < 128; ++i) {
    const float* xr = xb + (size_t)i * Lin + l;
    acc += xr[0] * wrow[i * 3 + 0] + xr[1] * wrow[i * 3 + 1] + xr[2] * wrow[i * 3 + 2];
  }
  out[((size_t)b * 128 + o) * Lout + l] = acc;
}

__global__ void maxpool_k(const float* __restrict__ in, float* __restrict__ out,
                          int Lin, int Lout, int k, int s, int total) {
  int idx = blockIdx.x * 256 + threadIdx.x;
  if (idx >= total) return;
  int j = idx % Lout;
  size_t row = idx / Lout;
  const float* r = in + row * Lin + (size_t)j * s;
  float m = r[0];
  for (int t = 1; t < k; ++t) m = fmaxf(m, r[t]);
  out[idx] = m;
}

// ---------------- small matmuls (M == 32 rows) ----------------
__global__ void small_mm(const float* __restrict__ A, const float* __restrict__ W,
                         const float* __restrict__ bias, float* __restrict__ C,
                         int M, int K, int Nc, int doRelu) {
  int row = threadIdx.x >> 3;
  int col = blockIdx.x * 8 + (threadIdx.x & 7);
  if (row >= M || col >= Nc) return;
  float acc = bias ? bias[col] : 0.f;
  for (int k = 0; k < K; ++k) acc += A[(size_t)row * K + k] * W[(size_t)k * Nc + col];
  if (doRelu) acc = fmaxf(acc, 0.f);
  C[(size_t)row * Nc + col] = acc;
}

__global__ void fuse_k(const float* __restrict__ g1fc, const float* __restrict__ seq1,
                       const float* __restrict__ w1, float* __restrict__ gc) {
  int i = blockIdx.x * 256 + threadIdx.x;
  if (i >= BB * 128) return;
  float wv = 1.f / (1.f + __expf(-w1[0]));
  gc[i] = (1.f - wv) * g1fc[i] + wv * seq1[i];
}

__global__ void head_k(const float* __restrict__ gc2, const float* __restrict__ ow,
                       const float* __restrict__ ob, float* __restrict__ out) {
  int b = threadIdx.x;
  if (b >= BB) return;
  float o0 = ob[0], o1 = ob[1];
  for (int k = 0; k < 256; ++k) {
    float v = gc2[b * 256 + k];
    o0 += v * ow[k * 2 + 0];
    o1 += v * ow[k * 2 + 1];
  }
  o0 = fmaxf(o0, 0.f); o1 = fmaxf(o1, 0.f);
  float mm = fmaxf(o0, o1);
  float e0 = __expf(o0 - mm), e1 = __expf(o1 - mm);
  float inv = 1.f / (e0 + e1);
  out[b * 2 + 0] = e0 * inv;
  out[b * 2 + 1] = e1 * inv;
}

extern "C" void kernel_launch(void* const* d_in, const int* in_sizes, int n_in,
                              void* d_out, int out_size, void* d_ws, size_t ws_size,
                              hipStream_t stream) {
  const float* node_feat = (const float*)d_in[0];
  const int*   src  = (const int*)d_in[1];
  const int*   dst  = (const int*)d_in[2];
  const int*   gids = (const int*)d_in[3];
  const float* pad  = (const float*)d_in[4];
  const float* W1   = (const float*)d_in[5];
  const float* al1  = (const float*)d_in[6];
  const float* ar1  = (const float*)d_in[7];
  const float* b1   = (const float*)d_in[8];
  const float* W2   = (const float*)d_in[9];
  const float* al2  = (const float*)d_in[10];
  const float* ar2  = (const float*)d_in[11];
  const float* b2   = (const float*)d_in[12];
  const float* fcgw = (const float*)d_in[13];
  const float* fcgb = (const float*)d_in[14];
  const float* c1w  = (const float*)d_in[15];
  const float* c1b  = (const float*)d_in[16];
  const float* c2w  = (const float*)d_in[17];
  const float* c2b  = (const float*)d_in[18];
  const float* c3w  = (const float*)d_in[19];
  const float* c3b  = (const float*)d_in[20];
  const float* tfw  = (const float*)d_in[21];
  const float* tfb  = (const float*)d_in[22];
  const float* w1s  = (const float*)d_in[23];
  const float* fc1w = (const float*)d_in[24];
  const float* fc1b = (const float*)d_in[25];
  const float* fc2w = (const float*)d_in[26];
  const float* fc2b = (const float*)d_in[27];
  const float* outw = (const float*)d_in[28];
  const float* outb = (const float*)d_in[29];
  float* out = (float*)d_out;
  char* base = (char*)d_ws;

  // -------- workspace layout (bytes) --------
  constexpr size_t SZ_BIG = (size_t)NN * HD * 2;          // 76.8 MB
  unsigned short* hA = (unsigned short*)(base + 0);       // region A
  unsigned short* gB = (unsigned short*)(base + SZ_BIG);  // region B
  unsigned short* nfbf = gB;  // bf16 node_feat, aliases region B (dead before agg1)
  size_t o = 2 * SZ_BIG;
  unsigned short* Wt1 = (unsigned short*)(base + o); o += 384 * 128 * 2;
  unsigned short* Wt2 = (unsigned short*)(base + o); o += 384 * 384 * 2;
  int* deg    = (int*)(base + o); o += (size_t)NN * 4;
  int* offs   = (int*)(base + o); o += (size_t)NN * 4;
  int* cursor = (int*)(base + o); o += (size_t)NN * 4;
  int* excl   = (int*)(base + o); o += (size_t)NN * 4;
  int* bsum   = (int*)(base + o); o += 2048;
  int* srcs   = (int*)(base + o); o += (size_t)EE * 4;
  float* el1  = (float*)(base + o); o += (size_t)NN * NH * 4;
  float* er1  = (float*)(base + o); o += (size_t)NN * NH * 4;
  float* el2  = (float*)(base + o); o += (size_t)NN * 4;
  float* er2  = (float*)(base + o); o += (size_t)NN * 4;
  unsigned* gpool = (unsigned*)(base + o); o += (size_t)BB * HD * 4;
  float* g1fc = (float*)(base + o); o += BB * 128 * 4;
  float* fvec = (float*)(base + o); o += BB * 128 * 4;
  float* seq1 = (float*)(base + o); o += BB * 128 * 4;
  float* gcv  = (float*)(base + o); o += BB * 128 * 4;
  float* gc1  = (float*)(base + o); o += BB * 512 * 4;
  float* gc2  = (float*)(base + o); o += BB * 256 * 4;

  // CNN scratch inside region A (dead before gemm1 writes hA)
  float* xT = (float*)base;
  float* c1 = xT + (size_t)BB * 128 * LSEQ;
  float* p1 = c1 + (size_t)BB * 128 * 998;
  float* c2 = p1 + (size_t)BB * 128 * 332;
  float* p2 = c2 + (size_t)BB * 128 * 330;
  float* c3 = p2 + (size_t)BB * 128 * 110;

  // -------- weight conversions --------
  f2bf_vec<<<(NN * DD / 4 + 255) / 256, 256, 0, stream>>>(node_feat, nfbf, NN * DD / 4);
  transp_w<<<(128 * 384 + 255) / 256, 256, 0, stream>>>(W1, Wt1, 128, 384);
  transp_w<<<(384 * 384 + 255) / 256, 256, 0, stream>>>(W2, Wt2, 384, 384);

  // -------- CNN branch --------
  {
    size_t tot = (size_t)BB * 128 * LSEQ;
    transpose_x<<<(int)((tot + 255) / 256), 256, 0, stream>>>(pad, xT);
  }
  conv1d_k<<<dim3(4, 128, BB), 256, 0, stream>>>(xT, LSEQ, c1w, c1b, c1, 998);
  {
    int tot = BB * 128 * 332;
    maxpool_k<<<(tot + 255) / 256, 256, 0, stream>>>(c1, p1, 998, 332, 3, 3, tot);
  }
  conv1d_k<<<dim3(2, 128, BB), 256, 0, stream>>>(p1, 332, c2w, c2b, c2, 330);
  {
    int tot = BB * 128 * 110;
    maxpool_k<<<(tot + 255) / 256, 256, 0, stream>>>(c2, p2, 330, 110, 3, 3, tot);
  }
  conv1d_k<<<dim3(1, 128, BB), 256, 0, stream>>>(p2, 110, c3w, c3b, c3, 108);
  {
    int tot = BB * 128;
    maxpool_k<<<(tot + 255) / 256, 256, 0, stream>>>(c3, fvec, 108, 1, 108, 1, tot);
  }
  small_mm<<<16, 256, 0, stream>>>(fvec, tfw, tfb, seq1, 32, 128, 128, 1);

  // -------- CSR build --------
  fill_u32<<<NB1, 256, 0, stream>>>((unsigned*)deg, 0u, NN);
  hist_k<<<EE / 256, 256, 0, stream>>>(dst, deg);
  scan1_k<<<NB1, 256, 0, stream>>>(deg, excl, bsum);
  scan2_k<<<1, 64, 0, stream>>>(bsum);
  scan3_k<<<NB1, 256, 0, stream>>>(excl, bsum, offs, cursor);
  scatter_k<<<EE / 256, 256, 0, stream>>>(src, dst, cursor, srcs);

  // -------- GAT layer 1 --------
  gemm_mfma<<<dim3(3, (NN + 127) / 128), 256, 0, stream>>>(nfbf, Wt1, hA, NN, 128, HD);
  elr_k1<<<(NN * NH * 64 + 255) / 256, 256, 0, stream>>>(hA, al1, ar1, el1, er1);
  agg_csr2<3><<<NN / 4, 256, 0, stream>>>(offs, deg, srcs, el1, er1, hA, b1, gB);

  // -------- GAT layer 2 --------
  gemm_mfma<<<dim3(3, (NN + 127) / 128), 256, 0, stream>>>(gB, Wt2, hA, NN, HD, HD);
  elr_k2<<<(NN * 64 + 255) / 256, 256, 0, stream>>>(hA, al2, ar2, el2, er2);
  agg_csr2<1><<<NN / 4, 256, 0, stream>>>(offs, deg, srcs, el2, er2, hA, b2, gB);

  // -------- graph pooling + head --------
  fill_u32<<<(BB * HD + 255) / 256, 256, 0, stream>>>(gpool, 0u, BB * HD);
  graph_pool<<<(NN + 63) / 64, 384, 0, stream>>>(gB, gids, gpool);
  small_mm<<<16, 256, 0, stream>>>((const float*)gpool, fcgw, fcgb, g1fc, 32, HD, 128, 1);
  fuse_k<<<16, 256, 0, stream>>>(g1fc, seq1, w1s, gcv);
  small_mm<<<64, 256, 0, stream>>>(gcv, fc1w, fc1b, gc1, 32, 128, 512, 1);
  small_mm<<<32, 256, 0, stream>>>(gc1, fc2w, fc2b, gc2, 32, 512, 256, 1);
  head_k<<<1, 64, 0, stream>>>(gc2, outw, outb, out);
}

// Round 4
// 1810.673 us; speedup vs baseline: 1.6227x; 1.1625x over previous
//
#include <hip/hip_runtime.h>
#include <math.h>

constexpr int NN = 100000;   // nodes
constexpr int EE = 3200000;  // edges
constexpr int BB = 32;       // graphs
constexpr int LSEQ = 1000;   // text length
constexpr int DD = 128;      // emb dim
constexpr int NH = 3;        // heads gat1
constexpr int HD = 384;      // 3*128
constexpr int NB1 = (NN + 255) / 256;  // scan blocks

typedef __attribute__((ext_vector_type(8))) short bf16v8;
typedef __attribute__((ext_vector_type(4))) float f32x4;

static __device__ __forceinline__ float lrelu(float x) { return x > 0.f ? x : 0.2f * x; }
static __device__ __forceinline__ float bf2f(unsigned short u) {
  return __uint_as_float(((unsigned)u) << 16);
}
static __device__ __forceinline__ unsigned short f2bf(float f) {
  unsigned x = __float_as_uint(f);
  return (unsigned short)((x + 0x7fffu + ((x >> 16) & 1u)) >> 16);
}

// ---------------- fills / converts ----------------
__global__ void fill_u32(unsigned* p, unsigned v, int n) {
  int i = blockIdx.x * 256 + threadIdx.x;
  if (i < n) p[i] = v;
}

__global__ void f2bf_vec(const float* __restrict__ in, unsigned short* __restrict__ out, int n4) {
  int i = blockIdx.x * 256 + threadIdx.x;
  if (i >= n4) return;
  float4 v = ((const float4*)in)[i];
  ushort4 o;
  o.x = f2bf(v.x); o.y = f2bf(v.y); o.z = f2bf(v.z); o.w = f2bf(v.w);
  ((ushort4*)out)[i] = o;
}

// out[n*K+k] = bf16(in[k*N+n])   (transpose + convert, small weights)
__global__ void transp_w(const float* __restrict__ in, unsigned short* __restrict__ out,
                         int K, int N) {
  int id = blockIdx.x * 256 + threadIdx.x;
  if (id >= K * N) return;
  int n = id / K, k = id % K;
  out[id] = f2bf(in[(size_t)k * N + n]);
}

// conv weight repack: in OIH [o][i][t] -> out [o][t*128+i], bf16
__global__ void transp_conv(const float* __restrict__ w, unsigned short* __restrict__ out) {
  int id = blockIdx.x * 256 + threadIdx.x;
  if (id >= 128 * 384) return;
  int o = id / 384, rem = id % 384;
  int t = rem / 128, i = rem % 128;
  out[id] = f2bf(w[(size_t)o * 384 + i * 3 + t]);
}

// ---------------- CSR build ----------------
__global__ void hist_k(const int* __restrict__ dst, int* __restrict__ deg) {
  int e = blockIdx.x * 256 + threadIdx.x;
  if (e < EE) atomicAdd(&deg[dst[e]], 1);
}

__global__ void scan1_k(const int* __restrict__ deg, int* __restrict__ excl,
                        int* __restrict__ bsum) {
  __shared__ int tmp[256];
  int tid = threadIdx.x;
  int i = blockIdx.x * 256 + tid;
  int v = (i < NN) ? deg[i] : 0;
  tmp[tid] = v;
  __syncthreads();
  for (int off = 1; off < 256; off <<= 1) {
    int t = (tid >= off) ? tmp[tid - off] : 0;
    __syncthreads();
    tmp[tid] += t;
    __syncthreads();
  }
  if (i < NN) excl[i] = tmp[tid] - v;
  if (tid == 255) bsum[blockIdx.x] = tmp[255];
}

__global__ void scan2_k(int* __restrict__ bsum) {
  if (threadIdx.x == 0 && blockIdx.x == 0) {
    int acc = 0;
    for (int b = 0; b < NB1; ++b) { int t = bsum[b]; bsum[b] = acc; acc += t; }
  }
}

__global__ void scan3_k(const int* __restrict__ excl, const int* __restrict__ bsum,
                        int* __restrict__ offs, int* __restrict__ cursor) {
  int i = blockIdx.x * 256 + threadIdx.x;
  if (i < NN) {
    int o = excl[i] + bsum[blockIdx.x];
    offs[i] = o;
    cursor[i] = o;
  }
}

__global__ void scatter_k(const int* __restrict__ src, const int* __restrict__ dst,
                          int* __restrict__ cursor, int* __restrict__ srcs) {
  int e = blockIdx.x * 256 + threadIdx.x;
  if (e >= EE) return;
  int pos = atomicAdd(&cursor[dst[e]], 1);
  srcs[pos] = src[e];
}

// ---------------- MFMA bf16 GEMM (generalized) ----------------
// C[z][M,Nc] = A[z][M rows, lda stride; K-window contiguous] @ Bt[Nc,K]^T (+bias)
// 128x128 tile, BK=64, 4 waves (2x2), global_load_lds w/ pre-swizzled source.
__global__ __launch_bounds__(256) void gemm_mfma(const unsigned short* __restrict__ A,
                                                 int lda,
                                                 const unsigned short* __restrict__ Bt,
                                                 unsigned short* __restrict__ C,
                                                 int M, int K, int Nc,
                                                 const float* __restrict__ bias,
                                                 long aBatch, long cBatch) {
  __shared__ unsigned short As[128 * 64];
  __shared__ unsigned short Bs[128 * 64];
  int lane = threadIdx.x & 63;
  int wave = threadIdx.x >> 6;
  int wm = wave >> 1, wn = wave & 1;
  int tile_m = blockIdx.y * 128;
  int tile_n = blockIdx.x * 128;
  int maxRa = M - 1 - tile_m;           // row clamping for loads (stores masked)
  f32x4 acc[4][4];
#pragma unroll
  for (int i = 0; i < 4; ++i)
#pragma unroll
    for (int j = 0; j < 4; ++j) acc[i][j] = (f32x4){0.f, 0.f, 0.f, 0.f};

  const unsigned short* Ab = A + (size_t)blockIdx.z * aBatch + (size_t)tile_m * lda;
  unsigned short* Cb = C + (size_t)blockIdx.z * cBatch;
  const unsigned short* Bb = Bt + (size_t)tile_n * K;
  int rloc = (lane >> 3);               // 0..7 within instr
  int cs = (lane & 7) ^ rloc;           // swizzled source chunk (inverse of read XOR)

  for (int k0 = 0; k0 < K; k0 += 64) {
#pragma unroll
    for (int q = 0; q < 4; ++q) {
      int t = wave * 4 + q;
      int r = t * 8 + rloc;
      int ra = r > maxRa ? maxRa : r;
      __builtin_amdgcn_global_load_lds(
          (const __attribute__((address_space(1))) void*)(Ab + (size_t)ra * lda + k0 + cs * 8),
          (__attribute__((address_space(3))) void*)(As + t * 512), 16, 0, 0);
      __builtin_amdgcn_global_load_lds(
          (const __attribute__((address_space(1))) void*)(Bb + (size_t)r * K + k0 + cs * 8),
          (__attribute__((address_space(3))) void*)(Bs + t * 512), 16, 0, 0);
    }
    __syncthreads();
#pragma unroll
    for (int ks = 0; ks < 2; ++ks) {
      int q = ks * 4 + (lane >> 4);
      bf16v8 af[4], bfr[4];
#pragma unroll
      for (int i = 0; i < 4; ++i) {
        int r = wm * 64 + i * 16 + (lane & 15);
        af[i] = *(const bf16v8*)&As[r * 64 + ((q ^ (r & 7)) * 8)];
      }
#pragma unroll
      for (int j = 0; j < 4; ++j) {
        int r = wn * 64 + j * 16 + (lane & 15);
        bfr[j] = *(const bf16v8*)&Bs[r * 64 + ((q ^ (r & 7)) * 8)];
      }
#pragma unroll
      for (int i = 0; i < 4; ++i)
#pragma unroll
        for (int j = 0; j < 4; ++j)
          acc[i][j] = __builtin_amdgcn_mfma_f32_16x16x32_bf16(af[i], bfr[j], acc[i][j], 0, 0, 0);
    }
    __syncthreads();
  }
#pragma unroll
  for (int i = 0; i < 4; ++i) {
    int row0 = tile_m + wm * 64 + i * 16 + (lane >> 4) * 4;
#pragma unroll
    for (int j = 0; j < 4; ++j) {
      int col = tile_n + wn * 64 + j * 16 + (lane & 15);
      float bv = bias ? bias[col] : 0.f;
#pragma unroll
      for (int p = 0; p < 4; ++p) {
        int row = row0 + p;
        if (row < M) Cb[(size_t)row * Nc + col] = f2bf(acc[i][j][p] + bv);
      }
    }
  }
}

// ---------------- el/er (padded to stride 4 for H=3) ----------------
__global__ void elr_k1(const unsigned short* __restrict__ h, const float* __restrict__ al,
                       const float* __restrict__ ar, float* __restrict__ el,
                       float* __restrict__ er) {
  int wid = (blockIdx.x * 256 + threadIdx.x) >> 6;
  int lane = threadIdx.x & 63;
  if (wid >= NN * NH) return;
  int n = wid / NH, hh = wid % NH;
  const unsigned short* row = h + (size_t)n * HD + hh * DD;
  const float* a = al + hh * DD;
  const float* r = ar + hh * DD;
  int c = lane * 2;
  unsigned v = *(const unsigned*)(row + c);
  float x0 = bf2f((unsigned short)(v & 0xffffu));
  float x1 = bf2f((unsigned short)(v >> 16));
  float pel = x0 * a[c] + x1 * a[c + 1];
  float per = x0 * r[c] + x1 * r[c + 1];
#pragma unroll
  for (int off = 32; off; off >>= 1) {
    pel += __shfl_down(pel, off);
    per += __shfl_down(per, off);
  }
  if (lane == 0) { el[n * 4 + hh] = pel; er[n * 4 + hh] = per; }
}

__global__ void elr_k2(const unsigned short* __restrict__ h, const float* __restrict__ al,
                       const float* __restrict__ ar, float* __restrict__ el,
                       float* __restrict__ er) {
  int wid = (blockIdx.x * 256 + threadIdx.x) >> 6;
  int lane = threadIdx.x & 63;
  if (wid >= NN) return;
  const unsigned short* row = h + (size_t)wid * HD;
  float pel = 0.f, per = 0.f;
#pragma unroll
  for (int k = 0; k < 3; ++k) {
    int c = lane * 2 + k * 128;
    unsigned v = *(const unsigned*)(row + c);
    float x0 = bf2f((unsigned short)(v & 0xffffu));
    float x1 = bf2f((unsigned short)(v >> 16));
    pel += x0 * al[c] + x1 * al[c + 1];
    per += x0 * ar[c] + x1 * ar[c + 1];
  }
#pragma unroll
  for (int off = 32; off; off >>= 1) {
    pel += __shfl_down(pel, off);
    per += __shfl_down(per, off);
  }
  if (lane == 0) { el[wid] = pel; er[wid] = per; }
}

// ---------------- fused edge softmax + aggregation, v3 ----------------
// wave per dst node; 1 dwordx4 el-gather per edge; row gather = dwordx2+dword/lane.
// EL stride: 4 for H=3, 1 for H=1.
template <int H>
static __device__ __forceinline__ void agg_body3(const float4 t,
                                                 const unsigned short* __restrict__ hfeat,
                                                 int lane, float acc[6]) {
  int s2 = __float_as_int(t.w);
  const unsigned short* hrow = hfeat + (size_t)s2 * HD;
  uint2 va = *(const uint2*)(hrow + lane * 4);                // cols lane*4..+3
  unsigned vb = *(const unsigned*)(hrow + 256 + lane * 2);    // cols 256+lane*2..+1
  float wa = (H == 3) ? ((lane < 32) ? t.x : t.y) : t.x;
  float wc = (H == 3) ? t.z : t.x;
  acc[0] += wa * bf2f((unsigned short)(va.x & 0xffffu));
  acc[1] += wa * bf2f((unsigned short)(va.x >> 16));
  acc[2] += wa * bf2f((unsigned short)(va.y & 0xffffu));
  acc[3] += wa * bf2f((unsigned short)(va.y >> 16));
  acc[4] += wc * bf2f((unsigned short)(vb & 0xffffu));
  acc[5] += wc * bf2f((unsigned short)(vb >> 16));
}

template <int H>
static __device__ __forceinline__ void load_sc(const float* __restrict__ el,
                                               int s, const float erd[H], float sc[H]) {
  if constexpr (H == 3) {
    float4 e = ((const float4*)el)[s];
    sc[0] = lrelu(e.x + erd[0]);
    sc[1] = lrelu(e.y + erd[1]);
    sc[2] = lrelu(e.z + erd[2]);
  } else {
    sc[0] = lrelu(el[s] + erd[0]);
  }
}

template <int H>
__global__ __launch_bounds__(256) void agg_csr3(const int* __restrict__ offs,
                                                const int* __restrict__ deg,
                                                const int* __restrict__ srcs,
                                                const float* __restrict__ el,
                                                const float* __restrict__ er,
                                                const unsigned short* __restrict__ hfeat,
                                                const float* __restrict__ bias,
                                                unsigned short* __restrict__ outg) {
  __shared__ float wb[4][64][4];
  int wave = threadIdx.x >> 6, lane = threadIdx.x & 63;
  int d = blockIdx.x * 4 + wave;          // grid = NN/4 exactly
  int o0 = offs[d], dg = deg[d];
  float erd[H];
  if constexpr (H == 3) {
    float4 e = ((const float4*)er)[d];
    erd[0] = e.x; erd[1] = e.y; erd[2] = e.z;
  } else {
    erd[0] = er[d];
  }
  float acc[6] = {0.f, 0.f, 0.f, 0.f, 0.f, 0.f};
  float wsum[H];
#pragma unroll
  for (int h = 0; h < H; ++h) wsum[h] = 0.f;

  if (dg <= 64) {
    bool has = lane < dg;
    int s = has ? srcs[o0 + lane] : 0;
    float sc[H], mh[H];
    load_sc<H>(el, s, erd, sc);
#pragma unroll
    for (int h = 0; h < H; ++h) {
      if (!has) sc[h] = -1e30f;
      mh[h] = sc[h];
#pragma unroll
      for (int off = 1; off < 64; off <<= 1) mh[h] = fmaxf(mh[h], __shfl_xor(mh[h], off));
    }
    float w0 = 0.f, w1 = 0.f, w2 = 0.f;
    if (has) {
      w0 = __expf(sc[0] - mh[0]);
      if constexpr (H == 3) {
        w1 = __expf(sc[1] - mh[1]);
        w2 = __expf(sc[2] - mh[2]);
      }
    }
    wsum[0] = w0;
    if constexpr (H == 3) { wsum[1] = w1; wsum[2] = w2; }
    *(float4*)&wb[wave][lane][0] = make_float4(w0, w1, w2, __int_as_float(s));
#pragma unroll 8
    for (int j = 0; j < dg; ++j) {
      float4 t = *(const float4*)&wb[wave][j][0];
      agg_body3<H>(t, hfeat, lane, acc);
    }
  } else {
    float mh[H];
#pragma unroll
    for (int h = 0; h < H; ++h) mh[h] = -1e30f;
    for (int e = lane; e < dg; e += 64) {
      int s = srcs[o0 + e];
      float sc[H];
      load_sc<H>(el, s, erd, sc);
#pragma unroll
      for (int h = 0; h < H; ++h) mh[h] = fmaxf(mh[h], sc[h]);
    }
#pragma unroll
    for (int h = 0; h < H; ++h) {
#pragma unroll
      for (int off = 1; off < 64; off <<= 1) mh[h] = fmaxf(mh[h], __shfl_xor(mh[h], off));
    }
    int nch = (dg + 63) >> 6;
    for (int ch = 0; ch < nch; ++ch) {
      int e = ch * 64 + lane;
      bool has = e < dg;
      int s = has ? srcs[o0 + e] : 0;
      float sc[H];
      load_sc<H>(el, s, erd, sc);
      float w0 = 0.f, w1 = 0.f, w2 = 0.f;
      if (has) {
        w0 = __expf(sc[0] - mh[0]);
        if constexpr (H == 3) {
          w1 = __expf(sc[1] - mh[1]);
          w2 = __expf(sc[2] - mh[2]);
        }
      }
      wsum[0] += w0;
      if constexpr (H == 3) { wsum[1] += w1; wsum[2] += w2; }
      *(float4*)&wb[wave][lane][0] = make_float4(w0, w1, w2, __int_as_float(s));
      int cnt = min(64, dg - ch * 64);
#pragma unroll 8
      for (int j = 0; j < cnt; ++j) {
        float4 t = *(const float4*)&wb[wave][j][0];
        agg_body3<H>(t, hfeat, lane, acc);
      }
    }
  }
#pragma unroll
  for (int h = 0; h < H; ++h) {
#pragma unroll
    for (int off = 1; off < 64; off <<= 1) wsum[h] += __shfl_xor(wsum[h], off);
  }
  float swA = (H == 3) ? ((lane < 32) ? wsum[0] : wsum[1]) : wsum[0];
  float swC = (H == 3) ? wsum[H - 1] : wsum[0];
  float invA = (dg > 0) ? 1.f / swA : 0.f;
  float invC = (dg > 0) ? 1.f / swC : 0.f;
  unsigned short* orow = outg + (size_t)d * HD;
  int cA = lane * 4, cB = 256 + lane * 2;
  float r0 = fmaxf(acc[0] * invA + bias[cA + 0], 0.f);
  float r1 = fmaxf(acc[1] * invA + bias[cA + 1], 0.f);
  float r2 = fmaxf(acc[2] * invA + bias[cA + 2], 0.f);
  float r3 = fmaxf(acc[3] * invA + bias[cA + 3], 0.f);
  float r4 = fmaxf(acc[4] * invC + bias[cB + 0], 0.f);
  float r5 = fmaxf(acc[5] * invC + bias[cB + 1], 0.f);
  uint2 pa;
  pa.x = (unsigned)f2bf(r0) | ((unsigned)f2bf(r1) << 16);
  pa.y = (unsigned)f2bf(r2) | ((unsigned)f2bf(r3) << 16);
  *(uint2*)(orow + cA) = pa;
  *(unsigned*)(orow + cB) = (unsigned)f2bf(r4) | ((unsigned)f2bf(r5) << 16);
}

// ---------------- graph max pool (graph_ids sorted; values >= 0) ----------------
__global__ void graph_pool(const unsigned short* __restrict__ g, const int* __restrict__ gid,
                           unsigned* __restrict__ gp) {
  int c = threadIdx.x;              // 0..383
  int n0 = blockIdx.x * 64;
  int nend = min(n0 + 64, NN);
  int cur = gid[n0];
  float mx = 0.f;
  for (int n = n0; n < nend; ++n) {
    int gg = gid[n];
    if (gg != cur) {
      atomicMax(&gp[cur * HD + c], __float_as_uint(mx));
      cur = gg; mx = 0.f;
    }
    mx = fmaxf(mx, bf2f(g[(size_t)n * HD + c]));
  }
  atomicMax(&gp[cur * HD + c], __float_as_uint(mx));
}

// ---------------- CNN branch: bf16 NHC pools ----------------
__global__ void maxpool_nhc(const unsigned short* __restrict__ in, unsigned short* __restrict__ out,
                            int Lin, int Lout, int total) {
  int idx = blockIdx.x * 256 + threadIdx.x;
  if (idx >= total) return;
  int c = idx & 127;
  int j = (idx >> 7) % Lout;
  int b = idx / (128 * Lout);
  const unsigned short* p = in + ((size_t)b * Lin + j * 3) * 128 + c;
  float m = bf2f(p[0]);
  m = fmaxf(m, bf2f(p[128]));
  m = fmaxf(m, bf2f(p[256]));
  out[idx] = f2bf(m);
}

// global max over 108 rows -> fvec fp32 [32][128]
__global__ void gpool_c3(const unsigned short* __restrict__ in, float* __restrict__ fvec) {
  int idx = blockIdx.x * 256 + threadIdx.x;
  if (idx >= BB * 128) return;
  int c = idx & 127, b = idx >> 7;
  const unsigned short* p = in + (size_t)b * 108 * 128 + c;
  float m = bf2f(p[0]);
  for (int t = 1; t < 108; ++t) m = fmaxf(m, bf2f(p[t * 128]));
  fvec[idx] = m;
}

// ---------------- small matmuls (M == 32 rows) ----------------
__global__ void small_mm(const float* __restrict__ A, const float* __restrict__ W,
                         const float* __restrict__ bias, float* __restrict__ C,
                         int M, int K, int Nc, int doRelu) {
  int row = threadIdx.x >> 3;
  int col = blockIdx.x * 8 + (threadIdx.x & 7);
  if (row >= M || col >= Nc) return;
  float acc = bias ? bias[col] : 0.f;
  for (int k = 0; k < K; ++k) acc += A[(size_t)row * K + k] * W[(size_t)k * Nc + col];
  if (doRelu) acc = fmaxf(acc, 0.f);
  C[(size_t)row * Nc + col] = acc;
}

__global__ void fuse_k(const float* __restrict__ g1fc, const float* __restrict__ seq1,
                       const float* __restrict__ w1, float* __restrict__ gc) {
  int i = blockIdx.x * 256 + threadIdx.x;
  if (i >= BB * 128) return;
  float wv = 1.f / (1.f + __expf(-w1[0]));
  gc[i] = (1.f - wv) * g1fc[i] + wv * seq1[i];
}

__global__ void head_k(const float* __restrict__ gc2, const float* __restrict__ ow,
                       const float* __restrict__ ob, float* __restrict__ out) {
  int b = threadIdx.x;
  if (b >= BB) return;
  float o0 = ob[0], o1 = ob[1];
  for (int k = 0; k < 256; ++k) {
    float v = gc2[b * 256 + k];
    o0 += v * ow[k * 2 + 0];
    o1 += v * ow[k * 2 + 1];
  }
  o0 = fmaxf(o0, 0.f); o1 = fmaxf(o1, 0.f);
  float mm = fmaxf(o0, o1);
  float e0 = __expf(o0 - mm), e1 = __expf(o1 - mm);
  float inv = 1.f / (e0 + e1);
  out[b * 2 + 0] = e0 * inv;
  out[b * 2 + 1] = e1 * inv;
}

extern "C" void kernel_launch(void* const* d_in, const int* in_sizes, int n_in,
                              void* d_out, int out_size, void* d_ws, size_t ws_size,
                              hipStream_t stream) {
  const float* node_feat = (const float*)d_in[0];
  const int*   src  = (const int*)d_in[1];
  const int*   dst  = (const int*)d_in[2];
  const int*   gids = (const int*)d_in[3];
  const float* pad  = (const float*)d_in[4];
  const float* W1   = (const float*)d_in[5];
  const float* al1  = (const float*)d_in[6];
  const float* ar1  = (const float*)d_in[7];
  const float* b1   = (const float*)d_in[8];
  const float* W2   = (const float*)d_in[9];
  const float* al2  = (const float*)d_in[10];
  const float* ar2  = (const float*)d_in[11];
  const float* b2   = (const float*)d_in[12];
  const float* fcgw = (const float*)d_in[13];
  const float* fcgb = (const float*)d_in[14];
  const float* c1w  = (const float*)d_in[15];
  const float* c1b  = (const float*)d_in[16];
  const float* c2w  = (const float*)d_in[17];
  const float* c2b  = (const float*)d_in[18];
  const float* c3w  = (const float*)d_in[19];
  const float* c3b  = (const float*)d_in[20];
  const float* tfw  = (const float*)d_in[21];
  const float* tfb  = (const float*)d_in[22];
  const float* w1s  = (const float*)d_in[23];
  const float* fc1w = (const float*)d_in[24];
  const float* fc1b = (const float*)d_in[25];
  const float* fc2w = (const float*)d_in[26];
  const float* fc2b = (const float*)d_in[27];
  const float* outw = (const float*)d_in[28];
  const float* outb = (const float*)d_in[29];
  float* out = (float*)d_out;
  char* base = (char*)d_ws;

  // -------- workspace layout (bytes) --------
  constexpr size_t SZ_BIG = (size_t)NN * HD * 2;          // 76.8 MB
  unsigned short* hA = (unsigned short*)(base + 0);       // region A
  unsigned short* gB = (unsigned short*)(base + SZ_BIG);  // region B
  unsigned short* nfbf = gB;  // bf16 node_feat, aliases region B (dead before agg1)
  size_t o = 2 * SZ_BIG;
  unsigned short* Wt1 = (unsigned short*)(base + o); o += 384 * 128 * 2;
  unsigned short* Wt2 = (unsigned short*)(base + o); o += 384 * 384 * 2;
  unsigned short* Wc1 = (unsigned short*)(base + o); o += 128 * 384 * 2;
  unsigned short* Wc2 = (unsigned short*)(base + o); o += 128 * 384 * 2;
  unsigned short* Wc3 = (unsigned short*)(base + o); o += 128 * 384 * 2;
  int* deg    = (int*)(base + o); o += (size_t)NN * 4;
  int* offs   = (int*)(base + o); o += (size_t)NN * 4;
  int* cursor = (int*)(base + o); o += (size_t)NN * 4;
  int* excl   = (int*)(base + o); o += (size_t)NN * 4;
  int* bsum   = (int*)(base + o); o += 2048;
  int* srcs   = (int*)(base + o); o += (size_t)EE * 4;
  float* el1  = (float*)(base + o); o += (size_t)NN * 4 * 4;   // padded stride 4
  float* er1  = (float*)(base + o); o += (size_t)NN * 4 * 4;   // padded stride 4
  float* el2  = (float*)(base + o); o += (size_t)NN * 4;
  float* er2  = (float*)(base + o); o += (size_t)NN * 4;
  unsigned* gpool = (unsigned*)(base + o); o += (size_t)BB * HD * 4;
  float* g1fc = (float*)(base + o); o += BB * 128 * 4;
  float* fvec = (float*)(base + o); o += BB * 128 * 4;
  float* seq1 = (float*)(base + o); o += BB * 128 * 4;
  float* gcv  = (float*)(base + o); o += BB * 128 * 4;
  float* gc1  = (float*)(base + o); o += BB * 512 * 4;
  float* gc2  = (float*)(base + o); o += BB * 256 * 4;

  // CNN scratch inside region A (dead before gemm1 writes hA), all bf16 NHC
  unsigned short* padbf = (unsigned short*)base;                   // [32][1000][128]
  unsigned short* c1bf  = padbf + (size_t)BB * LSEQ * 128;         // [32][998][128]
  unsigned short* p1bf  = c1bf + (size_t)BB * 998 * 128;           // [32][332][128]
  unsigned short* c2bf  = p1bf + (size_t)BB * 332 * 128;           // [32][330][128]
  unsigned short* p2bf  = c2bf + (size_t)BB * 330 * 128;           // [32][110][128]
  unsigned short* c3bf  = p2bf + (size_t)BB * 110 * 128;           // [32][108][128]

  // -------- weight / input conversions --------
  f2bf_vec<<<(NN * DD / 4 + 255) / 256, 256, 0, stream>>>(node_feat, nfbf, NN * DD / 4);
  f2bf_vec<<<(BB * LSEQ * 128 / 4 + 255) / 256, 256, 0, stream>>>(pad, padbf, BB * LSEQ * 128 / 4);
  transp_w<<<(128 * 384 + 255) / 256, 256, 0, stream>>>(W1, Wt1, 128, 384);
  transp_w<<<(384 * 384 + 255) / 256, 256, 0, stream>>>(W2, Wt2, 384, 384);
  transp_conv<<<(128 * 384 + 255) / 256, 256, 0, stream>>>(c1w, Wc1);
  transp_conv<<<(128 * 384 + 255) / 256, 256, 0, stream>>>(c2w, Wc2);
  transp_conv<<<(128 * 384 + 255) / 256, 256, 0, stream>>>(c3w, Wc3);

  // -------- CNN branch: convs as batched tap-GEMMs --------
  gemm_mfma<<<dim3(1, 8, BB), 256, 0, stream>>>(padbf, 128, Wc1, c1bf, 998, 384, 128, c1b,
                                                (long)LSEQ * 128, (long)998 * 128);
  maxpool_nhc<<<(BB * 332 * 128 + 255) / 256, 256, 0, stream>>>(c1bf, p1bf, 998, 332, BB * 332 * 128);
  gemm_mfma<<<dim3(1, 3, BB), 256, 0, stream>>>(p1bf, 128, Wc2, c2bf, 330, 384, 128, c2b,
                                                (long)332 * 128, (long)330 * 128);
  maxpool_nhc<<<(BB * 110 * 128 + 255) / 256, 256, 0, stream>>>(c2bf, p2bf, 330, 110, BB * 110 * 128);
  gemm_mfma<<<dim3(1, 1, BB), 256, 0, stream>>>(p2bf, 128, Wc3, c3bf, 108, 384, 128, c3b,
                                                (long)110 * 128, (long)108 * 128);
  gpool_c3<<<(BB * 128 + 255) / 256, 256, 0, stream>>>(c3bf, fvec);
  small_mm<<<16, 256, 0, stream>>>(fvec, tfw, tfb, seq1, 32, 128, 128, 1);

  // -------- CSR build --------
  fill_u32<<<NB1, 256, 0, stream>>>((unsigned*)deg, 0u, NN);
  hist_k<<<EE / 256, 256, 0, stream>>>(dst, deg);
  scan1_k<<<NB1, 256, 0, stream>>>(deg, excl, bsum);
  scan2_k<<<1, 64, 0, stream>>>(bsum);
  scan3_k<<<NB1, 256, 0, stream>>>(excl, bsum, offs, cursor);
  scatter_k<<<EE / 256, 256, 0, stream>>>(src, dst, cursor, srcs);

  // -------- GAT layer 1 --------
  gemm_mfma<<<dim3(3, (NN + 127) / 128, 1), 256, 0, stream>>>(nfbf, 128, Wt1, hA, NN, 128, HD,
                                                              nullptr, 0L, 0L);
  elr_k1<<<(NN * NH * 64 + 255) / 256, 256, 0, stream>>>(hA, al1, ar1, el1, er1);
  agg_csr3<3><<<NN / 4, 256, 0, stream>>>(offs, deg, srcs, el1, er1, hA, b1, gB);

  // -------- GAT layer 2 --------
  gemm_mfma<<<dim3(3, (NN + 127) / 128, 1), 256, 0, stream>>>(gB, 384, Wt2, hA, NN, 384, HD,
                                                              nullptr, 0L, 0L);
  elr_k2<<<(NN * 64 + 255) / 256, 256, 0, stream>>>(hA, al2, ar2, el2, er2);
  agg_csr3<1><<<NN / 4, 256, 0, stream>>>(offs, deg, srcs, el2, er2, hA, b2, gB);

  // -------- graph pooling + head --------
  fill_u32<<<(BB * HD + 255) / 256, 256, 0, stream>>>(gpool, 0u, BB * HD);
  graph_pool<<<(NN + 63) / 64, 384, 0, stream>>>(gB, gids, gpool);
  small_mm<<<16, 256, 0, stream>>>((const float*)gpool, fcgw, fcgb, g1fc, 32, HD, 128, 1);
  fuse_k<<<16, 256, 0, stream>>>(g1fc, seq1, w1s, gcv);
  small_mm<<<64, 256, 0, stream>>>(gcv, fc1w, fc1b, gc1, 32, 128, 512, 1);
  small_mm<<<32, 256, 0, stream>>>(gc1, fc2w, fc2b, gc2, 32, 512, 256, 1);
  head_k<<<1, 64, 0, stream>>>(gc2, outw, outb, out);
}